// Round 1
// baseline (366.789 us; speedup 1.0000x reference)
//
#include <hip/hip_runtime.h>
#include <hip/hip_bf16.h>

// ---------- types ----------
typedef __attribute__((ext_vector_type(4))) float  f32x4;
typedef __attribute__((ext_vector_type(8))) short  s16x8;   // 8 bf16
typedef __attribute__((ext_vector_type(4))) short  s16x4;

__device__ __forceinline__ float bf2f(short v) {
    unsigned u = ((unsigned)(unsigned short)v) << 16;
    return __builtin_bit_cast(float, u);
}
__device__ __forceinline__ short f2bf(float f) {
    unsigned u = __builtin_bit_cast(unsigned, f);
    u += 0x7fff + ((u >> 16) & 1);          // RNE
    return (short)(u >> 16);
}

// Problem constants
#define BATCH 2
#define CCH   512
#define SSP   4096          // H*W
#define MROWS 8192          // B*S
#define NH    8
#define DH    64

// ---------- kernel 1: weight cast fp32 -> bf16 ----------
__global__ __launch_bounds__(256) void wcast_kernel(
    const float* __restrict__ qw, const float* __restrict__ pw,
    short* __restrict__ dq, short* __restrict__ dp)
{
    int idx = (blockIdx.x * 256 + threadIdx.x) * 8;   // 512 blocks -> 1,048,576 el
    const float* src; short* dst;
    if (idx < 786432) { src = qw + idx; dst = dq + idx; }
    else              { src = pw + (idx - 786432); dst = dp + (idx - 786432); }
    f32x4 a = *(const f32x4*)src;
    f32x4 b = *(const f32x4*)(src + 4);
    s16x8 o;
    o[0]=f2bf(a[0]); o[1]=f2bf(a[1]); o[2]=f2bf(a[2]); o[3]=f2bf(a[3]);
    o[4]=f2bf(b[0]); o[5]=f2bf(b[1]); o[6]=f2bf(b[2]); o[7]=f2bf(b[3]);
    *(s16x8*)dst = o;
}

// ---------- kernel 2: GroupNorm partial sums ----------
// grid 512 = 16 (b,g) * 32 chunks, block 256. Group data is contiguous 262144 floats.
__global__ __launch_bounds__(256) void gn_partial_kernel(
    const float* __restrict__ x, float* __restrict__ part)
{
    int bg = blockIdx.x >> 5, chunk = blockIdx.x & 31;
    const float* base = x + (size_t)bg * 262144 + chunk * 8192;
    int t = threadIdx.x, lane = t & 63, wave = t >> 6;
    float s = 0.f, ss = 0.f;
    #pragma unroll
    for (int k = 0; k < 8; ++k) {
        f32x4 v = *(const f32x4*)&base[k * 1024 + t * 4];
        #pragma unroll
        for (int j = 0; j < 4; ++j) { s += v[j]; ss += v[j] * v[j]; }
    }
    #pragma unroll
    for (int mask = 1; mask < 64; mask <<= 1) {
        s  += __shfl_xor(s,  mask);
        ss += __shfl_xor(ss, mask);
    }
    __shared__ float rs[4], rss[4];
    if (lane == 0) { rs[wave] = s; rss[wave] = ss; }
    __syncthreads();
    if (t == 0) {
        part[blockIdx.x * 2]     = rs[0] + rs[1] + rs[2] + rs[3];
        part[blockIdx.x * 2 + 1] = rss[0] + rss[1] + rss[2] + rss[3];
    }
}

// ---------- kernel 3: finalize mean/rstd ----------
__global__ void gn_final_kernel(const float* __restrict__ part, float* __restrict__ stats)
{
    int t = threadIdx.x;
    if (t < 16) {
        float s = 0.f, ss = 0.f;
        for (int c = 0; c < 32; ++c) {
            s  += part[(t * 32 + c) * 2];
            ss += part[(t * 32 + c) * 2 + 1];
        }
        float mean = s * (1.f / 262144.f);
        float var  = ss * (1.f / 262144.f) - mean * mean;
        stats[t * 2]     = mean;
        stats[t * 2 + 1] = rsqrtf(var + 1e-5f);
    }
}

// ---------- kernel 4: normalize + transpose -> h[M=8192][K=512] bf16 ----------
// grid 1024: id = b*512 + ct*64 + st ; tile 64 ch x 64 sp
__global__ __launch_bounds__(256) void gn_apply_kernel(
    const float* __restrict__ x, const float* __restrict__ gw, const float* __restrict__ gb,
    const float* __restrict__ stats, short* __restrict__ hbuf)
{
    __shared__ float tile[64][65];
    int id = blockIdx.x;
    int st = id & 63, ct = (id >> 6) & 7, b = id >> 9;
    int t  = threadIdx.x;
    float mean = stats[(b * 8 + ct) * 2], rstd = stats[(b * 8 + ct) * 2 + 1];
    #pragma unroll
    for (int pass = 0; pass < 4; ++pass) {
        int cr = pass * 16 + (t >> 4);
        int c  = ct * 64 + cr;
        f32x4 v = *(const f32x4*)&x[((size_t)(b * CCH + c)) * SSP + st * 64 + (t & 15) * 4];
        float w  = gw[c] * rstd;
        float bb = gb[c] - mean * w;
        #pragma unroll
        for (int j = 0; j < 4; ++j) tile[cr][(t & 15) * 4 + j] = v[j] * w + bb;
    }
    __syncthreads();
    int sr = t >> 2, cc0 = (t & 3) * 16;
    s16x8 o0, o1;
    #pragma unroll
    for (int j = 0; j < 8; ++j) {
        o0[j] = f2bf(tile[cc0 + j][sr]);
        o1[j] = f2bf(tile[cc0 + 8 + j][sr]);
    }
    short* dst = &hbuf[(size_t)(b * SSP + st * 64 + sr) * CCH + ct * 64 + cc0];
    *(s16x8*)dst = o0;
    *(s16x8*)(dst + 8) = o1;
}

// ---------- GEMM: C[M,N] = A[M,K] * Bt[N,K]^T, bf16 in, fp32 acc ----------
// 128x128 tile, BK=32, 4 waves (2x2), fragment-linear LDS (conflict-free).
// EPI 0: qkv epilogue (cols<1024 -> qk buf pixel-major; cols>=1024 -> v transposed to vt)
// EPI 1: proj epilogue (transpose to NCHW + residual + bias, fp32 out)
template<int EPI>
__global__ __launch_bounds__(256) void gemm_bt_kernel(
    const short* __restrict__ A, const short* __restrict__ Bt,
    const float* __restrict__ bias,
    short* __restrict__ qkout, short* __restrict__ vtout,
    const float* __restrict__ xres, float* __restrict__ out,
    int K)
{
    __shared__ short As[4096], Bs[4096];
    const int t = threadIdx.x;
    const int lane = t & 63, wave = t >> 6;
    const int wm = wave >> 1, wn = wave & 1;
    const int m0 = blockIdx.x * 128, n0 = blockIdx.y * 128;
    const int l15 = lane & 15, lq = lane >> 4;

    f32x4 acc[4][4];
    #pragma unroll
    for (int i = 0; i < 4; ++i)
        #pragma unroll
        for (int j = 0; j < 4; ++j) acc[i][j] = (f32x4){0.f, 0.f, 0.f, 0.f};

    for (int kk = 0; kk < K; kk += 32) {
        __syncthreads();
        #pragma unroll
        for (int i = 0; i < 2; ++i) {
            int idx = i * 256 + t;
            int row = idx >> 2, cb = idx & 3;
            int dst = ((row >> 4) << 9) + ((((row & 15)) | (cb << 4)) << 3);
            *(s16x8*)&As[dst] = *(const s16x8*)&A [(size_t)(m0 + row) * K + kk + cb * 8];
            *(s16x8*)&Bs[dst] = *(const s16x8*)&Bt[(size_t)(n0 + row) * K + kk + cb * 8];
        }
        __syncthreads();
        s16x8 af[4], bfr[4];
        #pragma unroll
        for (int mt = 0; mt < 4; ++mt) af[mt]  = *(const s16x8*)&As[(((wm * 4 + mt) << 9) + lane * 8)];
        #pragma unroll
        for (int nt = 0; nt < 4; ++nt) bfr[nt] = *(const s16x8*)&Bs[(((wn * 4 + nt) << 9) + lane * 8)];
        #pragma unroll
        for (int mt = 0; mt < 4; ++mt)
            #pragma unroll
            for (int nt = 0; nt < 4; ++nt)
                acc[mt][nt] = __builtin_amdgcn_mfma_f32_16x16x32_bf16(af[mt], bfr[nt], acc[mt][nt], 0, 0, 0);
    }

    #pragma unroll
    for (int mt = 0; mt < 4; ++mt) {
        const int r0 = m0 + wm * 64 + mt * 16 + lq * 4;   // 4 consecutive m-rows
        #pragma unroll
        for (int nt = 0; nt < 4; ++nt) {
            const int c = n0 + wn * 64 + nt * 16 + l15;
            float bv = bias[c];
            if (EPI == 0) {
                if (c < 1024) {
                    #pragma unroll
                    for (int i = 0; i < 4; ++i)
                        qkout[(size_t)(r0 + i) * 1024 + c] = f2bf(acc[mt][nt][i] + bv);
                } else {
                    int cc = c - 1024;
                    int b = r0 >> 12, s = r0 & 4095;
                    s16x4 pv;
                    #pragma unroll
                    for (int i = 0; i < 4; ++i) pv[i] = f2bf(acc[mt][nt][i] + bv);
                    *(s16x4*)&vtout[(size_t)(b * 512 + cc) * SSP + s] = pv;
                }
            } else {
                int b = r0 >> 12, s = r0 & 4095;
                size_t xi = (size_t)(b * CCH + c) * SSP + s;
                f32x4 xv = *(const f32x4*)&xres[xi];
                f32x4 o  = xv + acc[mt][nt] + bv;
                *(f32x4*)&out[xi] = o;
            }
        }
    }
}

// ---------- kernel 6: flash attention ----------
// grid (64, 16): x = q-tile (64 rows / block, 16 per wave), y = b*8+h
// qk: [M][1024] bf16 (q at col h*64, k at col 512+h*64) ; vt: [(b*8+h)*64+d][4096]
__global__ __launch_bounds__(256) void attn_kernel(
    const short* __restrict__ qk, const short* __restrict__ vt,
    short* __restrict__ ao)
{
    __shared__ short Ks[4096], Vs[4096];
    __shared__ short Ps[4][16 * 72];          // per-wave P scratch, pad 8
    const int t = threadIdx.x, lane = t & 63, wave = t >> 6;
    const int bh = blockIdx.y, b = bh >> 3, h = bh & 7;
    const int q0 = blockIdx.x * 64 + wave * 16;
    const int l15 = lane & 15, lq = lane >> 4;

    // Q fragments, prescaled by dh^-0.5 = 0.125 (exact in bf16)
    s16x8 qf[2];
    {
        const short* qp = qk + (size_t)(b * SSP + q0 + l15) * 1024 + h * 64;
        #pragma unroll
        for (int ks = 0; ks < 2; ++ks) {
            s16x8 raw = *(const s16x8*)(qp + ks * 32 + lq * 8);
            #pragma unroll
            for (int j = 0; j < 8; ++j) qf[ks][j] = f2bf(bf2f(raw[j]) * 0.125f);
        }
    }

    f32x4 oacc[4];
    #pragma unroll
    for (int i = 0; i < 4; ++i) oacc[i] = (f32x4){0.f, 0.f, 0.f, 0.f};
    float m_[4], l_[4];
    #pragma unroll
    for (int i = 0; i < 4; ++i) { m_[i] = -__builtin_inff(); l_[i] = 0.f; }

    const short* kbase = qk + (size_t)(b * SSP) * 1024 + 512 + h * 64;
    const short* vbase = vt + (size_t)(b * 512 + h * 64) * SSP;
    short* pw = &Ps[wave][0];

    for (int t0 = 0; t0 < SSP; t0 += 64) {
        __syncthreads();
        #pragma unroll
        for (int i = 0; i < 2; ++i) {
            int idx = i * 256 + t;
            int rr = idx >> 3, cb = idx & 7;   // rr: K-row t / V-row d ; cb: 8-el chunk
            int dst = ((((rr >> 4) * 2 + (cb >> 2)) << 9) + ((((rr & 15)) | ((cb & 3) << 4)) << 3));
            *(s16x8*)&Ks[dst] = *(const s16x8*)&kbase[(size_t)(t0 + rr) * 1024 + cb * 8];
            *(s16x8*)&Vs[dst] = *(const s16x8*)&vbase[(size_t)rr * SSP + t0 + cb * 8];
        }
        __syncthreads();

        // S = Q K^T (scaled)
        f32x4 sacc[4];
        #pragma unroll
        for (int i = 0; i < 4; ++i) sacc[i] = (f32x4){0.f, 0.f, 0.f, 0.f};
        #pragma unroll
        for (int ks = 0; ks < 2; ++ks)
            #pragma unroll
            for (int nt = 0; nt < 4; ++nt) {
                s16x8 kf = *(const s16x8*)&Ks[((nt * 2 + ks) << 9) + lane * 8];
                sacc[nt] = __builtin_amdgcn_mfma_f32_16x16x32_bf16(qf[ks], kf, sacc[nt], 0, 0, 0);
            }

        // online softmax (rows = lq*4+i, cols spread over 16-lane group)
        float corr[4];
        #pragma unroll
        for (int i = 0; i < 4; ++i) {
            float mx = fmaxf(fmaxf(sacc[0][i], sacc[1][i]), fmaxf(sacc[2][i], sacc[3][i]));
            mx = fmaxf(mx, __shfl_xor(mx, 1));
            mx = fmaxf(mx, __shfl_xor(mx, 2));
            mx = fmaxf(mx, __shfl_xor(mx, 4));
            mx = fmaxf(mx, __shfl_xor(mx, 8));
            float mn = fmaxf(m_[i], mx);
            corr[i] = __expf(m_[i] - mn);
            m_[i] = mn;
        }
        float pp[4][4];
        #pragma unroll
        for (int nt = 0; nt < 4; ++nt)
            #pragma unroll
            for (int i = 0; i < 4; ++i) pp[nt][i] = __expf(sacc[nt][i] - m_[i]);
        #pragma unroll
        for (int i = 0; i < 4; ++i) {
            float s = pp[0][i] + pp[1][i] + pp[2][i] + pp[3][i];
            s += __shfl_xor(s, 1);
            s += __shfl_xor(s, 2);
            s += __shfl_xor(s, 4);
            s += __shfl_xor(s, 8);
            l_[i] = l_[i] * corr[i] + s;
        }
        #pragma unroll
        for (int nt = 0; nt < 4; ++nt)
            #pragma unroll
            for (int i = 0; i < 4; ++i) oacc[nt][i] *= corr[i];

        // P -> LDS (C-layout) then read back as A-fragments
        #pragma unroll
        for (int nt = 0; nt < 4; ++nt)
            #pragma unroll
            for (int i = 0; i < 4; ++i)
                pw[(lq * 4 + i) * 72 + nt * 16 + l15] = f2bf(pp[nt][i]);

        #pragma unroll
        for (int ks2 = 0; ks2 < 2; ++ks2) {
            s16x8 pa = *(const s16x8*)&pw[l15 * 72 + ks2 * 32 + lq * 8];
            #pragma unroll
            for (int nt2 = 0; nt2 < 4; ++nt2) {
                s16x8 vf = *(const s16x8*)&Vs[((nt2 * 2 + ks2) << 9) + lane * 8];
                oacc[nt2] = __builtin_amdgcn_mfma_f32_16x16x32_bf16(pa, vf, oacc[nt2], 0, 0, 0);
            }
        }
    }

    #pragma unroll
    for (int i = 0; i < 4; ++i) {
        float inv = 1.f / l_[i];
        int row = q0 + lq * 4 + i;
        #pragma unroll
        for (int nt2 = 0; nt2 < 4; ++nt2)
            ao[(size_t)(b * SSP + row) * CCH + h * 64 + nt2 * 16 + l15] = f2bf(oacc[nt2][i] * inv);
    }
}

// ---------- launch ----------
extern "C" void kernel_launch(void* const* d_in, const int* in_sizes, int n_in,
                              void* d_out, int out_size, void* d_ws, size_t ws_size,
                              hipStream_t stream)
{
    (void)in_sizes; (void)n_in; (void)out_size; (void)ws_size;
    const float* x      = (const float*)d_in[0];
    const float* gn_w   = (const float*)d_in[1];
    const float* gn_b   = (const float*)d_in[2];
    const float* qkv_w  = (const float*)d_in[3];
    const float* qkv_b  = (const float*)d_in[4];
    const float* proj_w = (const float*)d_in[5];
    const float* proj_b = (const float*)d_in[6];
    float* out = (float*)d_out;
    char* ws = (char*)d_ws;

    short* hbuf  = (short*)(ws + 0);          //  8,388,608  h[8192][512]
    short* qkbuf = (short*)(ws + 8388608);    // 16,777,216  qk[8192][1024]
    short* vtbuf = (short*)(ws + 25165824);   //  8,388,608  vt[1024][4096]
    short* aobuf = (short*)(ws + 33554432);   //  8,388,608  ao[8192][512]
    short* wqkv  = (short*)(ws + 41943040);   //  1,572,864
    short* wproj = (short*)(ws + 43515904);   //    524,288
    float* part  = (float*)(ws + 44040192);   //      4,096
    float* stats = (float*)(ws + 44044288);   //        128

    wcast_kernel<<<512, 256, 0, stream>>>(qkv_w, proj_w, wqkv, wproj);
    gn_partial_kernel<<<512, 256, 0, stream>>>(x, part);
    gn_final_kernel<<<1, 64, 0, stream>>>(part, stats);
    gn_apply_kernel<<<1024, 256, 0, stream>>>(x, gn_w, gn_b, stats, hbuf);
    gemm_bt_kernel<0><<<dim3(64, 12), 256, 0, stream>>>(hbuf, wqkv, qkv_b,
                                                        qkbuf, vtbuf, nullptr, nullptr, 512);
    attn_kernel<<<dim3(64, 16), 256, 0, stream>>>(qkbuf, vtbuf, aobuf);
    gemm_bt_kernel<1><<<dim3(64, 4), 256, 0, stream>>>(aobuf, wproj, proj_b,
                                                       nullptr, nullptr, x, out, 512);
}

// Round 2
// 193.582 us; speedup vs baseline: 1.8948x; 1.8948x over previous
//
#include <hip/hip_runtime.h>
#include <hip/hip_bf16.h>

// ---------- types ----------
typedef __attribute__((ext_vector_type(4))) float  f32x4;
typedef __attribute__((ext_vector_type(8))) short  s16x8;   // 8 bf16
typedef __attribute__((ext_vector_type(4))) short  s16x4;

__device__ __forceinline__ float bf2f(short v) {
    unsigned u = ((unsigned)(unsigned short)v) << 16;
    return __builtin_bit_cast(float, u);
}
__device__ __forceinline__ short f2bf(float f) {
    unsigned u = __builtin_bit_cast(unsigned, f);
    u += 0x7fff + ((u >> 16) & 1);          // RNE
    return (short)(u >> 16);
}
__device__ __forceinline__ unsigned cvt_pk_bf16(float lo, float hi) {
    unsigned r;
    asm("v_cvt_pk_bf16_f32 %0, %1, %2" : "=v"(r) : "v"(lo), "v"(hi));
    return r;
}
__device__ __forceinline__ void gload16(const short* g, short* l) {
    __builtin_amdgcn_global_load_lds(
        (const __attribute__((address_space(1))) void*)g,
        (__attribute__((address_space(3))) void*)l, 16, 0, 0);
}

// Problem constants
#define BATCH 2
#define CCH   512
#define SSP   4096          // H*W
#define MROWS 8192          // B*S
#define NH    8
#define DH    64

// ---------- kernel 1: weight cast fp32 -> bf16 ----------
__global__ __launch_bounds__(256) void wcast_kernel(
    const float* __restrict__ qw, const float* __restrict__ pw,
    short* __restrict__ dq, short* __restrict__ dp)
{
    int idx = (blockIdx.x * 256 + threadIdx.x) * 8;
    const float* src; short* dst;
    if (idx < 786432) { src = qw + idx; dst = dq + idx; }
    else              { src = pw + (idx - 786432); dst = dp + (idx - 786432); }
    f32x4 a = *(const f32x4*)src;
    f32x4 b = *(const f32x4*)(src + 4);
    s16x8 o;
    o[0]=f2bf(a[0]); o[1]=f2bf(a[1]); o[2]=f2bf(a[2]); o[3]=f2bf(a[3]);
    o[4]=f2bf(b[0]); o[5]=f2bf(b[1]); o[6]=f2bf(b[2]); o[7]=f2bf(b[3]);
    *(s16x8*)dst = o;
}

// ---------- kernel 2: GroupNorm partial sums ----------
__global__ __launch_bounds__(256) void gn_partial_kernel(
    const float* __restrict__ x, float* __restrict__ part)
{
    int bg = blockIdx.x >> 5, chunk = blockIdx.x & 31;
    const float* base = x + (size_t)bg * 262144 + chunk * 8192;
    int t = threadIdx.x, lane = t & 63, wave = t >> 6;
    float s = 0.f, ss = 0.f;
    #pragma unroll
    for (int k = 0; k < 8; ++k) {
        f32x4 v = *(const f32x4*)&base[k * 1024 + t * 4];
        #pragma unroll
        for (int j = 0; j < 4; ++j) { s += v[j]; ss += v[j] * v[j]; }
    }
    #pragma unroll
    for (int mask = 1; mask < 64; mask <<= 1) {
        s  += __shfl_xor(s,  mask);
        ss += __shfl_xor(ss, mask);
    }
    __shared__ float rs[4], rss[4];
    if (lane == 0) { rs[wave] = s; rss[wave] = ss; }
    __syncthreads();
    if (t == 0) {
        part[blockIdx.x * 2]     = rs[0] + rs[1] + rs[2] + rs[3];
        part[blockIdx.x * 2 + 1] = rss[0] + rss[1] + rss[2] + rss[3];
    }
}

// ---------- kernel 3: finalize mean/rstd ----------
__global__ void gn_final_kernel(const float* __restrict__ part, float* __restrict__ stats)
{
    int t = threadIdx.x;
    if (t < 16) {
        float s = 0.f, ss = 0.f;
        for (int c = 0; c < 32; ++c) {
            s  += part[(t * 32 + c) * 2];
            ss += part[(t * 32 + c) * 2 + 1];
        }
        float mean = s * (1.f / 262144.f);
        float var  = ss * (1.f / 262144.f) - mean * mean;
        stats[t * 2]     = mean;
        stats[t * 2 + 1] = rsqrtf(var + 1e-5f);
    }
}

// ---------- kernel 4: normalize + transpose -> h[M=8192][K=512] bf16 ----------
__global__ __launch_bounds__(256) void gn_apply_kernel(
    const float* __restrict__ x, const float* __restrict__ gw, const float* __restrict__ gb,
    const float* __restrict__ stats, short* __restrict__ hbuf)
{
    __shared__ float tile[64][65];
    int id = blockIdx.x;
    int st = id & 63, ct = (id >> 6) & 7, b = id >> 9;
    int t  = threadIdx.x;
    float mean = stats[(b * 8 + ct) * 2], rstd = stats[(b * 8 + ct) * 2 + 1];
    #pragma unroll
    for (int pass = 0; pass < 4; ++pass) {
        int cr = pass * 16 + (t >> 4);
        int c  = ct * 64 + cr;
        f32x4 v = *(const f32x4*)&x[((size_t)(b * CCH + c)) * SSP + st * 64 + (t & 15) * 4];
        float w  = gw[c] * rstd;
        float bb = gb[c] - mean * w;
        #pragma unroll
        for (int j = 0; j < 4; ++j) tile[cr][(t & 15) * 4 + j] = v[j] * w + bb;
    }
    __syncthreads();
    int sr = t >> 2, cc0 = (t & 3) * 16;
    s16x8 o0, o1;
    #pragma unroll
    for (int j = 0; j < 8; ++j) {
        o0[j] = f2bf(tile[cc0 + j][sr]);
        o1[j] = f2bf(tile[cc0 + 8 + j][sr]);
    }
    short* dst = &hbuf[(size_t)(b * SSP + st * 64 + sr) * CCH + ct * 64 + cc0];
    *(s16x8*)dst = o0;
    *(s16x8*)(dst + 8) = o1;
}

// ---------- GEMM: C[M,N] = A[M,K] * Bt[N,K]^T, bf16 in, fp32 acc ----------
// EPI 0: qkv epilogue (Q pixel-major [8192][512]; K/V to fragment-linear bufs)
// EPI 1: proj epilogue (transpose to NCHW + residual + bias, fp32 out)
template<int EPI>
__global__ __launch_bounds__(256) void gemm_bt_kernel(
    const short* __restrict__ A, const short* __restrict__ Bt,
    const float* __restrict__ bias,
    short* __restrict__ qout, short* __restrict__ kout, short* __restrict__ vout,
    const float* __restrict__ xres, float* __restrict__ out,
    int K)
{
    __shared__ short As[4096], Bs[4096];
    const int t = threadIdx.x;
    const int lane = t & 63, wave = t >> 6;
    const int wm = wave >> 1, wn = wave & 1;
    const int m0 = blockIdx.x * 128, n0 = blockIdx.y * 128;
    const int l15 = lane & 15, lq = lane >> 4;

    f32x4 acc[4][4];
    #pragma unroll
    for (int i = 0; i < 4; ++i)
        #pragma unroll
        for (int j = 0; j < 4; ++j) acc[i][j] = (f32x4){0.f, 0.f, 0.f, 0.f};

    for (int kk = 0; kk < K; kk += 32) {
        __syncthreads();
        #pragma unroll
        for (int i = 0; i < 2; ++i) {
            int idx = i * 256 + t;
            int row = idx >> 2, cb = idx & 3;
            int dst = ((row >> 4) << 9) + ((((row & 15)) | (cb << 4)) << 3);
            *(s16x8*)&As[dst] = *(const s16x8*)&A [(size_t)(m0 + row) * K + kk + cb * 8];
            *(s16x8*)&Bs[dst] = *(const s16x8*)&Bt[(size_t)(n0 + row) * K + kk + cb * 8];
        }
        __syncthreads();
        s16x8 af[4], bfr[4];
        #pragma unroll
        for (int mt = 0; mt < 4; ++mt) af[mt]  = *(const s16x8*)&As[(((wm * 4 + mt) << 9) + lane * 8)];
        #pragma unroll
        for (int nt = 0; nt < 4; ++nt) bfr[nt] = *(const s16x8*)&Bs[(((wn * 4 + nt) << 9) + lane * 8)];
        #pragma unroll
        for (int mt = 0; mt < 4; ++mt)
            #pragma unroll
            for (int nt = 0; nt < 4; ++nt)
                acc[mt][nt] = __builtin_amdgcn_mfma_f32_16x16x32_bf16(af[mt], bfr[nt], acc[mt][nt], 0, 0, 0);
    }

    #pragma unroll
    for (int mt = 0; mt < 4; ++mt) {
        const int r0 = m0 + wm * 64 + mt * 16 + lq * 4;   // 4 consecutive m-rows
        #pragma unroll
        for (int nt = 0; nt < 4; ++nt) {
            const int c = n0 + wn * 64 + nt * 16 + l15;
            float bv = bias[c];
            if (EPI == 0) {
                int bb = r0 >> 12, tloc = r0 & 4095;
                if (c < 512) {
                    #pragma unroll
                    for (int i = 0; i < 4; ++i)
                        qout[(size_t)(r0 + i) * 512 + c] = f2bf(acc[mt][nt][i] + bv);
                } else if (c < 1024) {
                    int hh = (c - 512) >> 6, d = (c - 512) & 63;
                    int ks = d >> 5, chunkd = (d & 31) >> 3, jj = d & 7;
                    size_t sub = ((size_t)(bb * 8 + hh) * 256 + (tloc >> 4)) * 2 + ks;
                    #pragma unroll
                    for (int i = 0; i < 4; ++i) {
                        int pos16 = ((tloc + i) & 15) + 16 * chunkd;
                        kout[sub * 512 + pos16 * 8 + jj] = f2bf(acc[mt][nt][i] + bv);
                    }
                } else {
                    int hh = (c - 1024) >> 6, d = (c - 1024) & 63;
                    int tile = tloc >> 6, ks2 = (tloc & 63) >> 5, cbl = (tloc & 31) >> 3;
                    int dt = d >> 4, pos16 = (d & 15) + 16 * cbl;
                    size_t sub = ((size_t)(bb * 8 + hh) * 64 + tile) * 8 + dt * 2 + ks2;
                    s16x4 pv;
                    #pragma unroll
                    for (int i = 0; i < 4; ++i) pv[i] = f2bf(acc[mt][nt][i] + bv);
                    *(s16x4*)&vout[sub * 512 + pos16 * 8 + (tloc & 7)] = pv;
                }
            } else {
                int bb = r0 >> 12, s = r0 & 4095;
                size_t xi = (size_t)(bb * CCH + c) * SSP + s;
                f32x4 xv = *(const f32x4*)&xres[xi];
                f32x4 o  = xv + acc[mt][nt] + bv;
                *(f32x4*)&out[xi] = o;
            }
        }
    }
}

// ---------- kernel 6: flash attention (swapped-operand, dbuf, gload_lds) ----------
// grid (32, 16): x = q-tile (128 rows/block, 32/wave), y = b*8+h
// qbuf [8192][512]; kfrag [bh][256 t-tiles][2 ks][512]; vfrag [bh][64 tiles][8 sub][512]
__global__ __launch_bounds__(256) void attn_kernel(
    const short* __restrict__ qbuf, const short* __restrict__ kfrag,
    const short* __restrict__ vfrag, short* __restrict__ ao)
{
    __shared__ short Ks[2][4096];
    __shared__ short Vs[2][4096];
    __shared__ short Ps[4][2048];
    const int t = threadIdx.x, lane = t & 63, wave = t >> 6;
    const int bh = blockIdx.y, b = bh >> 3, h = bh & 7;
    const int q0w = blockIdx.x * 128 + wave * 32;
    const int l15 = lane & 15, lq = lane >> 4;

    // Q fragments (B-operand: col=q, k=d), prescaled by dh^-0.5
    s16x8 qf[2][2];
    #pragma unroll
    for (int qt = 0; qt < 2; ++qt) {
        const short* qp = qbuf + (size_t)(b * SSP + q0w + qt * 16 + l15) * 512 + h * 64;
        #pragma unroll
        for (int ks = 0; ks < 2; ++ks) {
            s16x8 raw = *(const s16x8*)(qp + ks * 32 + lq * 8);
            #pragma unroll
            for (int j = 0; j < 8; ++j) qf[qt][ks][j] = f2bf(bf2f(raw[j]) * 0.125f);
        }
    }

    const short* kbase = kfrag + (size_t)bh * 262144 + lane * 8;
    const short* vbase = vfrag + (size_t)bh * 262144 + lane * 8;

    f32x4 oacc[4][2];
    #pragma unroll
    for (int dt = 0; dt < 4; ++dt)
        #pragma unroll
        for (int qt = 0; qt < 2; ++qt) oacc[dt][qt] = (f32x4){0.f, 0.f, 0.f, 0.f};
    float m_[2], l_[2];
    m_[0] = m_[1] = -__builtin_inff();
    l_[0] = l_[1] = 0.f;

    // prologue stage
    {
        const short* kg = kbase + (size_t)(0 + wave) * 1024;
        gload16(kg,       &Ks[0][(wave * 2 + 0) * 512]);
        gload16(kg + 512, &Ks[0][(wave * 2 + 1) * 512]);
        const short* vg = vbase + (size_t)(0 * 8 + wave * 2) * 512;
        gload16(vg,       &Vs[0][(wave * 2 + 0) * 512]);
        gload16(vg + 512, &Vs[0][(wave * 2 + 1) * 512]);
    }
    asm volatile("s_waitcnt vmcnt(0)" ::: "memory");
    __syncthreads();

    int cur = 0;
    for (int t0 = 0; t0 < SSP; t0 += 64) {
        if (t0 + 64 < SSP) {
            int nb = cur ^ 1, tn = t0 + 64;
            const short* kg = kbase + (size_t)((tn >> 4) + wave) * 1024;
            gload16(kg,       &Ks[nb][(wave * 2 + 0) * 512]);
            gload16(kg + 512, &Ks[nb][(wave * 2 + 1) * 512]);
            const short* vg = vbase + (size_t)((tn >> 6) * 8 + wave * 2) * 512;
            gload16(vg,       &Vs[nb][(wave * 2 + 0) * 512]);
            gload16(vg + 512, &Vs[nb][(wave * 2 + 1) * 512]);
        }

        // ---- S^T = K * Q^T : sacc[tt][qt] row=t(lq*4+i), col=q(l15) ----
        f32x4 sacc[4][2];
        #pragma unroll
        for (int tt = 0; tt < 4; ++tt) {
            sacc[tt][0] = (f32x4){0.f, 0.f, 0.f, 0.f};
            sacc[tt][1] = (f32x4){0.f, 0.f, 0.f, 0.f};
        }
        #pragma unroll
        for (int ks = 0; ks < 2; ++ks)
            #pragma unroll
            for (int tt = 0; tt < 4; ++tt) {
                s16x8 kf = *(const s16x8*)&Ks[cur][(tt * 2 + ks) * 512 + lane * 8];
                sacc[tt][0] = __builtin_amdgcn_mfma_f32_16x16x32_bf16(kf, qf[0][ks], sacc[tt][0], 0, 0, 0);
                sacc[tt][1] = __builtin_amdgcn_mfma_f32_16x16x32_bf16(kf, qf[1][ks], sacc[tt][1], 0, 0, 0);
            }

        // ---- online softmax: all state lane-local at l15=q ----
        float corr[2];
        #pragma unroll
        for (int qt = 0; qt < 2; ++qt) {
            float mx = sacc[0][qt][0];
            #pragma unroll
            for (int tt = 0; tt < 4; ++tt)
                #pragma unroll
                for (int i = 0; i < 4; ++i) mx = fmaxf(mx, sacc[tt][qt][i]);
            mx = fmaxf(mx, __shfl_xor(mx, 16));
            mx = fmaxf(mx, __shfl_xor(mx, 32));
            float mn = fmaxf(m_[qt], mx);
            corr[qt] = __expf(m_[qt] - mn);
            m_[qt] = mn;
            float s = 0.f;
            #pragma unroll
            for (int tt = 0; tt < 4; ++tt)
                #pragma unroll
                for (int i = 0; i < 4; ++i) {
                    float e = __expf(sacc[tt][qt][i] - mn);
                    sacc[tt][qt][i] = e;
                    s += e;
                }
            s += __shfl_xor(s, 16);
            s += __shfl_xor(s, 32);
            l_[qt] = l_[qt] * corr[qt] + s;
        }
        #pragma unroll
        for (int dt = 0; dt < 4; ++dt) {
            #pragma unroll
            for (int i = 0; i < 4; ++i) {
                oacc[dt][0][i] *= corr[0];
                oacc[dt][1][i] *= corr[1];
            }
        }

        // ---- P pack -> fragment-linear LDS (per-wave) ----
        #pragma unroll
        for (int qt = 0; qt < 2; ++qt)
            #pragma unroll
            for (int tt = 0; tt < 4; ++tt) {
                unsigned pa = cvt_pk_bf16(sacc[tt][qt][0], sacc[tt][qt][1]);
                unsigned pb = cvt_pk_bf16(sacc[tt][qt][2], sacc[tt][qt][3]);
                int ks2 = tt >> 1, chunk = ((tt & 1) << 1) + (lq >> 1);
                unsigned* dst = (unsigned*)&Ps[wave][(qt * 2 + ks2) * 512 + (l15 + 16 * chunk) * 8 + (lq & 1) * 4];
                dst[0] = pa; dst[1] = pb;
            }

        // ---- O^T += V^T * P^T : oacc[dt][qt] row=d(lq*4+i), col=q(l15) ----
        #pragma unroll
        for (int ks2 = 0; ks2 < 2; ++ks2) {
            s16x8 pf0 = *(const s16x8*)&Ps[wave][(0 + ks2) * 512 + lane * 8];
            s16x8 pf1 = *(const s16x8*)&Ps[wave][(2 + ks2) * 512 + lane * 8];
            #pragma unroll
            for (int dt = 0; dt < 4; ++dt) {
                s16x8 vf = *(const s16x8*)&Vs[cur][(dt * 2 + ks2) * 512 + lane * 8];
                oacc[dt][0] = __builtin_amdgcn_mfma_f32_16x16x32_bf16(vf, pf0, oacc[dt][0], 0, 0, 0);
                oacc[dt][1] = __builtin_amdgcn_mfma_f32_16x16x32_bf16(vf, pf1, oacc[dt][1], 0, 0, 0);
            }
        }

        asm volatile("s_waitcnt vmcnt(0)" ::: "memory");
        __syncthreads();
        cur ^= 1;
    }

    // epilogue: O[q][d] with q=l15 (col), d=lq*4+i (row) -> 8B stores
    #pragma unroll
    for (int qt = 0; qt < 2; ++qt) {
        float linv = 1.f / l_[qt];
        #pragma unroll
        for (int dt = 0; dt < 4; ++dt) {
            s16x4 o;
            #pragma unroll
            for (int i = 0; i < 4; ++i) o[i] = f2bf(oacc[dt][qt][i] * linv);
            *(s16x4*)&ao[(size_t)(b * SSP + q0w + qt * 16 + l15) * 512 + h * 64 + dt * 16 + lq * 4] = o;
        }
    }
}

// ---------- launch ----------
extern "C" void kernel_launch(void* const* d_in, const int* in_sizes, int n_in,
                              void* d_out, int out_size, void* d_ws, size_t ws_size,
                              hipStream_t stream)
{
    (void)in_sizes; (void)n_in; (void)out_size; (void)ws_size;
    const float* x      = (const float*)d_in[0];
    const float* gn_w   = (const float*)d_in[1];
    const float* gn_b   = (const float*)d_in[2];
    const float* qkv_w  = (const float*)d_in[3];
    const float* qkv_b  = (const float*)d_in[4];
    const float* proj_w = (const float*)d_in[5];
    const float* proj_b = (const float*)d_in[6];
    float* out = (float*)d_out;
    char* ws = (char*)d_ws;

    short* hbuf  = (short*)(ws + 0);          //  8 MB  h[8192][512]
    short* qbuf  = (short*)(ws + 8388608);    //  8 MB  q[8192][512]
    short* kfrag = (short*)(ws + 16777216);   //  8 MB  k fragment-linear
    short* vfrag = (short*)(ws + 25165824);   //  8 MB  v fragment-linear
    short* aobuf = (short*)(ws + 33554432);   //  8 MB  ao[8192][512]
    short* wqkv  = (short*)(ws + 41943040);   //  1.5 MB
    short* wproj = (short*)(ws + 43515904);   //  0.5 MB
    float* part  = (float*)(ws + 44040192);
    float* stats = (float*)(ws + 44044288);

    wcast_kernel<<<512, 256, 0, stream>>>(qkv_w, proj_w, wqkv, wproj);
    gn_partial_kernel<<<512, 256, 0, stream>>>(x, part);
    gn_final_kernel<<<1, 64, 0, stream>>>(part, stats);
    gn_apply_kernel<<<1024, 256, 0, stream>>>(x, gn_w, gn_b, stats, hbuf);
    gemm_bt_kernel<0><<<dim3(64, 12), 256, 0, stream>>>(hbuf, wqkv, qkv_b,
                                                        qbuf, kfrag, vfrag, nullptr, nullptr, 512);
    attn_kernel<<<dim3(32, 16), 256, 0, stream>>>(qbuf, kfrag, vfrag, aobuf);
    gemm_bt_kernel<1><<<dim3(64, 4), 256, 0, stream>>>(aobuf, wproj, proj_b,
                                                       nullptr, nullptr, nullptr, x, out, 512);
}

// Round 3
// 182.387 us; speedup vs baseline: 2.0110x; 1.0614x over previous
//
#include <hip/hip_runtime.h>
#include <hip/hip_bf16.h>

// ---------- types ----------
typedef __attribute__((ext_vector_type(4))) float  f32x4;
typedef __attribute__((ext_vector_type(8))) short  s16x8;   // 8 bf16
typedef __attribute__((ext_vector_type(4))) short  s16x4;

__device__ __forceinline__ float bf2f(short v) {
    unsigned u = ((unsigned)(unsigned short)v) << 16;
    return __builtin_bit_cast(float, u);
}
__device__ __forceinline__ short f2bf(float f) {
    unsigned u = __builtin_bit_cast(unsigned, f);
    u += 0x7fff + ((u >> 16) & 1);          // RNE
    return (short)(u >> 16);
}
__device__ __forceinline__ unsigned cvt_pk_bf16(float lo, float hi) {
    unsigned r;
    asm("v_cvt_pk_bf16_f32 %0, %1, %2" : "=v"(r) : "v"(lo), "v"(hi));
    return r;
}
__device__ __forceinline__ float exp2_asm(float x) {
    float r; asm("v_exp_f32 %0, %1" : "=v"(r) : "v"(x)); return r;
}
__device__ __forceinline__ float log2_asm(float x) {
    float r; asm("v_log_f32 %0, %1" : "=v"(r) : "v"(x)); return r;
}
__device__ __forceinline__ void gload16(const short* g, short* l) {
    __builtin_amdgcn_global_load_lds(
        (const __attribute__((address_space(1))) void*)g,
        (__attribute__((address_space(3))) void*)l, 16, 0, 0);
}

// Problem constants
#define BATCH 2
#define CCH   512
#define SSP   4096          // H*W
#define NH    8
#define DH    64

// ---------- kernel 1: weight cast fp32 -> bf16 ----------
__global__ __launch_bounds__(256) void wcast_kernel(
    const float* __restrict__ qw, const float* __restrict__ pw,
    short* __restrict__ dq, short* __restrict__ dp)
{
    int idx = (blockIdx.x * 256 + threadIdx.x) * 8;
    const float* src; short* dst;
    if (idx < 786432) { src = qw + idx; dst = dq + idx; }
    else              { src = pw + (idx - 786432); dst = dp + (idx - 786432); }
    f32x4 a = *(const f32x4*)src;
    f32x4 b = *(const f32x4*)(src + 4);
    s16x8 o;
    o[0]=f2bf(a[0]); o[1]=f2bf(a[1]); o[2]=f2bf(a[2]); o[3]=f2bf(a[3]);
    o[4]=f2bf(b[0]); o[5]=f2bf(b[1]); o[6]=f2bf(b[2]); o[7]=f2bf(b[3]);
    *(s16x8*)dst = o;
}

// ---------- kernel 2: GroupNorm partial sums ----------
__global__ __launch_bounds__(256) void gn_partial_kernel(
    const float* __restrict__ x, float* __restrict__ part)
{
    int bg = blockIdx.x >> 5, chunk = blockIdx.x & 31;
    const float* base = x + (size_t)bg * 262144 + chunk * 8192;
    int t = threadIdx.x, lane = t & 63, wave = t >> 6;
    float s = 0.f, ss = 0.f;
    #pragma unroll
    for (int k = 0; k < 8; ++k) {
        f32x4 v = *(const f32x4*)&base[k * 1024 + t * 4];
        #pragma unroll
        for (int j = 0; j < 4; ++j) { s += v[j]; ss += v[j] * v[j]; }
    }
    #pragma unroll
    for (int mask = 1; mask < 64; mask <<= 1) {
        s  += __shfl_xor(s,  mask);
        ss += __shfl_xor(ss, mask);
    }
    __shared__ float rs[4], rss[4];
    if (lane == 0) { rs[wave] = s; rss[wave] = ss; }
    __syncthreads();
    if (t == 0) {
        part[blockIdx.x * 2]     = rs[0] + rs[1] + rs[2] + rs[3];
        part[blockIdx.x * 2 + 1] = rss[0] + rss[1] + rss[2] + rss[3];
    }
}

// ---------- kernel 3: finalize mean/rstd ----------
__global__ void gn_final_kernel(const float* __restrict__ part, float* __restrict__ stats)
{
    int t = threadIdx.x;
    if (t < 16) {
        float s = 0.f, ss = 0.f;
        for (int c = 0; c < 32; ++c) {
            s  += part[(t * 32 + c) * 2];
            ss += part[(t * 32 + c) * 2 + 1];
        }
        float mean = s * (1.f / 262144.f);
        float var  = ss * (1.f / 262144.f) - mean * mean;
        stats[t * 2]     = mean;
        stats[t * 2 + 1] = rsqrtf(var + 1e-5f);
    }
}

// ---------- kernel 4: normalize + transpose -> h[M=8192][K=512] bf16 ----------
__global__ __launch_bounds__(256) void gn_apply_kernel(
    const float* __restrict__ x, const float* __restrict__ gw, const float* __restrict__ gb,
    const float* __restrict__ stats, short* __restrict__ hbuf)
{
    __shared__ float tile[64][65];
    int id = blockIdx.x;
    int st = id & 63, ct = (id >> 6) & 7, b = id >> 9;
    int t  = threadIdx.x;
    float mean = stats[(b * 8 + ct) * 2], rstd = stats[(b * 8 + ct) * 2 + 1];
    #pragma unroll
    for (int pass = 0; pass < 4; ++pass) {
        int cr = pass * 16 + (t >> 4);
        int c  = ct * 64 + cr;
        f32x4 v = *(const f32x4*)&x[((size_t)(b * CCH + c)) * SSP + st * 64 + (t & 15) * 4];
        float w  = gw[c] * rstd;
        float bb = gb[c] - mean * w;
        #pragma unroll
        for (int j = 0; j < 4; ++j) tile[cr][(t & 15) * 4 + j] = v[j] * w + bb;
    }
    __syncthreads();
    int sr = t >> 2, cc0 = (t & 3) * 16;
    s16x8 o0, o1;
    #pragma unroll
    for (int j = 0; j < 8; ++j) {
        o0[j] = f2bf(tile[cc0 + j][sr]);
        o1[j] = f2bf(tile[cc0 + 8 + j][sr]);
    }
    short* dst = &hbuf[(size_t)(b * SSP + st * 64 + sr) * CCH + ct * 64 + cc0];
    *(s16x8*)dst = o0;
    *(s16x8*)(dst + 8) = o1;
}

// ---------- GEMM: C[M,N] = A[M,K] * Bt[N,K]^T, bf16 in, fp32 acc ----------
template<int EPI>
__global__ __launch_bounds__(256) void gemm_bt_kernel(
    const short* __restrict__ A, const short* __restrict__ Bt,
    const float* __restrict__ bias,
    short* __restrict__ qout, short* __restrict__ kout, short* __restrict__ vout,
    const float* __restrict__ xres, float* __restrict__ out,
    int K)
{
    __shared__ short As[4096], Bs[4096];
    const int t = threadIdx.x;
    const int lane = t & 63, wave = t >> 6;
    const int wm = wave >> 1, wn = wave & 1;
    const int m0 = blockIdx.x * 128, n0 = blockIdx.y * 128;
    const int l15 = lane & 15, lq = lane >> 4;

    f32x4 acc[4][4];
    #pragma unroll
    for (int i = 0; i < 4; ++i)
        #pragma unroll
        for (int j = 0; j < 4; ++j) acc[i][j] = (f32x4){0.f, 0.f, 0.f, 0.f};

    for (int kk = 0; kk < K; kk += 32) {
        __syncthreads();
        #pragma unroll
        for (int i = 0; i < 2; ++i) {
            int idx = i * 256 + t;
            int row = idx >> 2, cb = idx & 3;
            int dst = ((row >> 4) << 9) + ((((row & 15)) | (cb << 4)) << 3);
            *(s16x8*)&As[dst] = *(const s16x8*)&A [(size_t)(m0 + row) * K + kk + cb * 8];
            *(s16x8*)&Bs[dst] = *(const s16x8*)&Bt[(size_t)(n0 + row) * K + kk + cb * 8];
        }
        __syncthreads();
        s16x8 af[4], bfr[4];
        #pragma unroll
        for (int mt = 0; mt < 4; ++mt) af[mt]  = *(const s16x8*)&As[(((wm * 4 + mt) << 9) + lane * 8)];
        #pragma unroll
        for (int nt = 0; nt < 4; ++nt) bfr[nt] = *(const s16x8*)&Bs[(((wn * 4 + nt) << 9) + lane * 8)];
        #pragma unroll
        for (int mt = 0; mt < 4; ++mt)
            #pragma unroll
            for (int nt = 0; nt < 4; ++nt)
                acc[mt][nt] = __builtin_amdgcn_mfma_f32_16x16x32_bf16(af[mt], bfr[nt], acc[mt][nt], 0, 0, 0);
    }

    #pragma unroll
    for (int mt = 0; mt < 4; ++mt) {
        const int r0 = m0 + wm * 64 + mt * 16 + lq * 4;
        #pragma unroll
        for (int nt = 0; nt < 4; ++nt) {
            const int c = n0 + wn * 64 + nt * 16 + l15;
            float bv = bias[c];
            if (EPI == 0) {
                int bb = r0 >> 12, tloc = r0 & 4095;
                if (c < 512) {
                    #pragma unroll
                    for (int i = 0; i < 4; ++i)
                        qout[(size_t)(r0 + i) * 512 + c] = f2bf(acc[mt][nt][i] + bv);
                } else if (c < 1024) {
                    int hh = (c - 512) >> 6, d = (c - 512) & 63;
                    int ks = d >> 5, chunkd = (d & 31) >> 3, jj = d & 7;
                    size_t sub = ((size_t)(bb * 8 + hh) * 256 + (tloc >> 4)) * 2 + ks;
                    #pragma unroll
                    for (int i = 0; i < 4; ++i) {
                        int pos16 = ((tloc + i) & 15) + 16 * chunkd;
                        kout[sub * 512 + pos16 * 8 + jj] = f2bf(acc[mt][nt][i] + bv);
                    }
                } else {
                    int hh = (c - 1024) >> 6, d = (c - 1024) & 63;
                    int tile = tloc >> 6, ks2 = (tloc & 63) >> 5, cbl = (tloc & 31) >> 3;
                    int dt = d >> 4, pos16 = (d & 15) + 16 * cbl;
                    size_t sub = ((size_t)(bb * 8 + hh) * 64 + tile) * 8 + dt * 2 + ks2;
                    s16x4 pv;
                    #pragma unroll
                    for (int i = 0; i < 4; ++i) pv[i] = f2bf(acc[mt][nt][i] + bv);
                    *(s16x4*)&vout[sub * 512 + pos16 * 8 + (tloc & 7)] = pv;
                }
            } else {
                int bb = r0 >> 12, s = r0 & 4095;
                size_t xi = (size_t)(bb * CCH + c) * SSP + s;
                f32x4 xv = *(const f32x4*)&xres[xi];
                f32x4 o  = xv + acc[mt][nt] + bv;
                *(f32x4*)&out[xi] = o;
            }
        }
    }
}

// ---------- kernel 6: flash attention, kv-split x2, exp2 domain ----------
// grid (32, 32): x = q-tile (128 rows/block, 32/wave), y = half*16 + bh
// outputs: normalized partial O (bf16) + a = m + log2(l) per q-row
__global__ __launch_bounds__(256) void attn_kernel(
    const short* __restrict__ qbuf, const short* __restrict__ kfrag,
    const short* __restrict__ vfrag,
    short* __restrict__ p0, short* __restrict__ p1, float* __restrict__ aout)
{
    __shared__ short Ks[2][4096];
    __shared__ short Vs[2][4096];
    __shared__ short Ps[4][2048];
    const int t = threadIdx.x, lane = t & 63, wave = t >> 6;
    const int yy = blockIdx.y, bh = yy & 15, half = yy >> 4;
    const int b = bh >> 3;
    const int q0w = blockIdx.x * 128 + wave * 32;
    const int l15 = lane & 15, lq = lane >> 4;
    const int kv0 = half * 2048;

    // Q fragments (B-operand), prescaled by dh^-0.5 * log2(e)
    s16x8 qf[2][2];
    #pragma unroll
    for (int qt = 0; qt < 2; ++qt) {
        const short* qp = qbuf + (size_t)(b * SSP + q0w + qt * 16 + l15) * 512 + (yy & 7) * 64;
        #pragma unroll
        for (int ks = 0; ks < 2; ++ks) {
            s16x8 raw = *(const s16x8*)(qp + ks * 32 + lq * 8);
            #pragma unroll
            for (int j = 0; j < 8; ++j) qf[qt][ks][j] = f2bf(bf2f(raw[j]) * 0.18033688011112042f);
        }
    }

    const short* kbase = kfrag + (size_t)bh * 262144 + lane * 8;
    const short* vbase = vfrag + (size_t)bh * 262144 + lane * 8;

    f32x4 oacc[4][2];
    #pragma unroll
    for (int dt = 0; dt < 4; ++dt)
        #pragma unroll
        for (int qt = 0; qt < 2; ++qt) oacc[dt][qt] = (f32x4){0.f, 0.f, 0.f, 0.f};
    f32x4 lacc[2];
    lacc[0] = (f32x4){0.f, 0.f, 0.f, 0.f};
    lacc[1] = (f32x4){0.f, 0.f, 0.f, 0.f};
    float m_[2];
    m_[0] = m_[1] = -__builtin_inff();

    s16x8 ones;
    #pragma unroll
    for (int j = 0; j < 8; ++j) ones[j] = (short)0x3F80;

    // prologue stage
    {
        const short* kg = kbase + (size_t)((kv0 >> 4) + wave) * 1024;
        gload16(kg,       &Ks[0][(wave * 2 + 0) * 512]);
        gload16(kg + 512, &Ks[0][(wave * 2 + 1) * 512]);
        const short* vg = vbase + (size_t)((kv0 >> 6) * 8 + wave * 2) * 512;
        gload16(vg,       &Vs[0][(wave * 2 + 0) * 512]);
        gload16(vg + 512, &Vs[0][(wave * 2 + 1) * 512]);
    }
    asm volatile("s_waitcnt vmcnt(0)" ::: "memory");
    __syncthreads();

    int cur = 0;
    for (int t0 = kv0; t0 < kv0 + 2048; t0 += 64) {
        if (t0 + 64 < kv0 + 2048) {
            int nb = cur ^ 1, tn = t0 + 64;
            const short* kg = kbase + (size_t)((tn >> 4) + wave) * 1024;
            gload16(kg,       &Ks[nb][(wave * 2 + 0) * 512]);
            gload16(kg + 512, &Ks[nb][(wave * 2 + 1) * 512]);
            const short* vg = vbase + (size_t)((tn >> 6) * 8 + wave * 2) * 512;
            gload16(vg,       &Vs[nb][(wave * 2 + 0) * 512]);
            gload16(vg + 512, &Vs[nb][(wave * 2 + 1) * 512]);
        }

        // ---- S^T = K * Q^T (log2 domain) ----
        f32x4 sacc[4][2];
        #pragma unroll
        for (int tt = 0; tt < 4; ++tt) {
            sacc[tt][0] = (f32x4){0.f, 0.f, 0.f, 0.f};
            sacc[tt][1] = (f32x4){0.f, 0.f, 0.f, 0.f};
        }
        #pragma unroll
        for (int ks = 0; ks < 2; ++ks)
            #pragma unroll
            for (int tt = 0; tt < 4; ++tt) {
                s16x8 kf = *(const s16x8*)&Ks[cur][(tt * 2 + ks) * 512 + lane * 8];
                sacc[tt][0] = __builtin_amdgcn_mfma_f32_16x16x32_bf16(kf, qf[0][ks], sacc[tt][0], 0, 0, 0);
                sacc[tt][1] = __builtin_amdgcn_mfma_f32_16x16x32_bf16(kf, qf[1][ks], sacc[tt][1], 0, 0, 0);
            }

        // ---- softmax: defer-max + exp2 ----
        float mx[2];
        #pragma unroll
        for (int qt = 0; qt < 2; ++qt) {
            float a0 = fmaxf(fmaxf(sacc[0][qt][0], sacc[0][qt][1]), sacc[0][qt][2]);
            float a1 = fmaxf(fmaxf(sacc[0][qt][3], sacc[1][qt][0]), sacc[1][qt][1]);
            float a2 = fmaxf(fmaxf(sacc[1][qt][2], sacc[1][qt][3]), sacc[2][qt][0]);
            float a3 = fmaxf(fmaxf(sacc[2][qt][1], sacc[2][qt][2]), sacc[2][qt][3]);
            float a4 = fmaxf(fmaxf(sacc[3][qt][0], sacc[3][qt][1]), sacc[3][qt][2]);
            float b0 = fmaxf(fmaxf(a0, a1), a2);
            float b1 = fmaxf(fmaxf(a3, a4), sacc[3][qt][3]);
            mx[qt] = fmaxf(b0, b1);
        }
        int calm = __all((mx[0] <= m_[0] + 11.5f) && (mx[1] <= m_[1] + 11.5f));
        if (!calm) {
            #pragma unroll
            for (int qt = 0; qt < 2; ++qt) {
                float g = fmaxf(mx[qt], __shfl_xor(mx[qt], 16));
                g = fmaxf(g, __shfl_xor(g, 32));
                float mn = fmaxf(m_[qt], g);
                float corr = exp2_asm(m_[qt] - mn);
                m_[qt] = mn;
                #pragma unroll
                for (int dt = 0; dt < 4; ++dt)
                    #pragma unroll
                    for (int i = 0; i < 4; ++i) oacc[dt][qt][i] *= corr;
                #pragma unroll
                for (int i = 0; i < 4; ++i) lacc[qt][i] *= corr;
            }
        }
        #pragma unroll
        for (int qt = 0; qt < 2; ++qt)
            #pragma unroll
            for (int tt = 0; tt < 4; ++tt)
                #pragma unroll
                for (int i = 0; i < 4; ++i)
                    sacc[tt][qt][i] = exp2_asm(sacc[tt][qt][i] - m_[qt]);

        // ---- P pack -> fragment-linear LDS (per-wave) ----
        #pragma unroll
        for (int qt = 0; qt < 2; ++qt)
            #pragma unroll
            for (int tt = 0; tt < 4; ++tt) {
                unsigned pa = cvt_pk_bf16(sacc[tt][qt][0], sacc[tt][qt][1]);
                unsigned pb = cvt_pk_bf16(sacc[tt][qt][2], sacc[tt][qt][3]);
                int ks2 = tt >> 1, chunk = ((tt & 1) << 1) + (lq >> 1);
                unsigned* dst = (unsigned*)&Ps[wave][(qt * 2 + ks2) * 512 + (l15 + 16 * chunk) * 8 + (lq & 1) * 4];
                dst[0] = pa; dst[1] = pb;
            }

        // ---- O^T += V^T * P^T ; l via ones-MFMA ----
        #pragma unroll
        for (int ks2 = 0; ks2 < 2; ++ks2) {
            s16x8 pf0 = *(const s16x8*)&Ps[wave][(0 + ks2) * 512 + lane * 8];
            s16x8 pf1 = *(const s16x8*)&Ps[wave][(2 + ks2) * 512 + lane * 8];
            lacc[0] = __builtin_amdgcn_mfma_f32_16x16x32_bf16(ones, pf0, lacc[0], 0, 0, 0);
            lacc[1] = __builtin_amdgcn_mfma_f32_16x16x32_bf16(ones, pf1, lacc[1], 0, 0, 0);
            #pragma unroll
            for (int dt = 0; dt < 4; ++dt) {
                s16x8 vf = *(const s16x8*)&Vs[cur][(dt * 2 + ks2) * 512 + lane * 8];
                oacc[dt][0] = __builtin_amdgcn_mfma_f32_16x16x32_bf16(vf, pf0, oacc[dt][0], 0, 0, 0);
                oacc[dt][1] = __builtin_amdgcn_mfma_f32_16x16x32_bf16(vf, pf1, oacc[dt][1], 0, 0, 0);
            }
        }

        asm volatile("s_waitcnt vmcnt(0)" ::: "memory");
        __syncthreads();
        cur ^= 1;
    }

    // epilogue: normalized partial O + a = m + log2(l)
    short* pO = half ? p1 : p0;
    #pragma unroll
    for (int qt = 0; qt < 2; ++qt) {
        float l = lacc[qt][0];
        float linv = 1.f / l;
        int q = q0w + qt * 16 + l15;
        size_t base = ((size_t)bh * 4096 + q) * 64;
        #pragma unroll
        for (int dt = 0; dt < 4; ++dt) {
            s16x4 o;
            #pragma unroll
            for (int i = 0; i < 4; ++i) o[i] = f2bf(oacc[dt][qt][i] * linv);
            *(s16x4*)&pO[base + dt * 16 + lq * 4] = o;
        }
        if (lq == 0)
            aout[half * 65536 + bh * 4096 + q] = m_[qt] + log2_asm(l);
    }
}

// ---------- kernel 7: combine kv-split halves ----------
// grid 2048: bid -> bh = bid>>7, q0 = (bid&127)*32 ; thread: qr = t>>3, d0 = (t&7)*8
__global__ __launch_bounds__(256) void combine_kernel(
    const short* __restrict__ p0, const short* __restrict__ p1,
    const float* __restrict__ aout, short* __restrict__ ao)
{
    int bh = blockIdx.x >> 7, q = (blockIdx.x & 127) * 32 + (threadIdx.x >> 3);
    int d0 = (threadIdx.x & 7) * 8;
    size_t pi = ((size_t)bh * 4096 + q) * 64 + d0;
    s16x8 o1 = *(const s16x8*)&p0[pi];
    s16x8 o2 = *(const s16x8*)&p1[pi];
    float a1 = aout[bh * 4096 + q], a2 = aout[65536 + bh * 4096 + q];
    float M = fmaxf(a1, a2);
    float w1 = exp2_asm(a1 - M), w2 = exp2_asm(a2 - M);
    float inv = 1.f / (w1 + w2);
    w1 *= inv; w2 *= inv;
    s16x8 o;
    #pragma unroll
    for (int j = 0; j < 8; ++j) o[j] = f2bf(bf2f(o1[j]) * w1 + bf2f(o2[j]) * w2);
    int b = bh >> 3, h = bh & 7;
    *(s16x8*)&ao[(size_t)(b * SSP + q) * 512 + h * 64 + d0] = o;
}

// ---------- launch ----------
extern "C" void kernel_launch(void* const* d_in, const int* in_sizes, int n_in,
                              void* d_out, int out_size, void* d_ws, size_t ws_size,
                              hipStream_t stream)
{
    (void)in_sizes; (void)n_in; (void)out_size; (void)ws_size;
    const float* x      = (const float*)d_in[0];
    const float* gn_w   = (const float*)d_in[1];
    const float* gn_b   = (const float*)d_in[2];
    const float* qkv_w  = (const float*)d_in[3];
    const float* qkv_b  = (const float*)d_in[4];
    const float* proj_w = (const float*)d_in[5];
    const float* proj_b = (const float*)d_in[6];
    float* out = (float*)d_out;
    char* ws = (char*)d_ws;

    short* hbuf  = (short*)(ws + 0);          //  8 MB  h[8192][512]  (reused: partial O half 0)
    short* qbuf  = (short*)(ws + 8388608);    //  8 MB  q[8192][512]
    short* kfrag = (short*)(ws + 16777216);   //  8 MB  k fragment-linear (reused: combined O)
    short* vfrag = (short*)(ws + 25165824);   //  8 MB  v fragment-linear
    short* aobuf = (short*)(ws + 33554432);   //  8 MB  (partial O half 1)
    short* wqkv  = (short*)(ws + 41943040);   //  1.5 MB (reused: a-scalars 512KB)
    short* wproj = (short*)(ws + 43515904);   //  0.5 MB
    float* part  = (float*)(ws + 44040192);
    float* stats = (float*)(ws + 44044288);
    float* ascal = (float*)(ws + 41943040);

    wcast_kernel<<<512, 256, 0, stream>>>(qkv_w, proj_w, wqkv, wproj);
    gn_partial_kernel<<<512, 256, 0, stream>>>(x, part);
    gn_final_kernel<<<1, 64, 0, stream>>>(part, stats);
    gn_apply_kernel<<<1024, 256, 0, stream>>>(x, gn_w, gn_b, stats, hbuf);
    gemm_bt_kernel<0><<<dim3(64, 12), 256, 0, stream>>>(hbuf, wqkv, qkv_b,
                                                        qbuf, kfrag, vfrag, nullptr, nullptr, 512);
    attn_kernel<<<dim3(32, 32), 256, 0, stream>>>(qbuf, kfrag, vfrag,
                                                  hbuf, aobuf, ascal);
    combine_kernel<<<2048, 256, 0, stream>>>(hbuf, aobuf, ascal, kfrag);
    gemm_bt_kernel<1><<<dim3(64, 4), 256, 0, stream>>>(kfrag, wproj, proj_b,
                                                       nullptr, nullptr, nullptr, x, out, 512);
}

// Round 4
// 158.662 us; speedup vs baseline: 2.3118x; 1.1495x over previous
//
#include <hip/hip_runtime.h>
#include <hip/hip_bf16.h>

// ---------- types ----------
typedef __attribute__((ext_vector_type(4)))  float  f32x4;
typedef __attribute__((ext_vector_type(16))) float  f32x16;
typedef __attribute__((ext_vector_type(8)))  short  s16x8;   // 8 bf16
typedef __attribute__((ext_vector_type(4)))  short  s16x4;
typedef __attribute__((ext_vector_type(4)))  unsigned u32x4;
typedef __attribute__((ext_vector_type(2)))  unsigned u32x2;

__device__ __forceinline__ float bf2f(short v) {
    unsigned u = ((unsigned)(unsigned short)v) << 16;
    return __builtin_bit_cast(float, u);
}
__device__ __forceinline__ short f2bf(float f) {
    unsigned u = __builtin_bit_cast(unsigned, f);
    u += 0x7fff + ((u >> 16) & 1);          // RNE
    return (short)(u >> 16);
}
__device__ __forceinline__ unsigned cvt_pk_bf16(float lo, float hi) {
    unsigned r;
    asm("v_cvt_pk_bf16_f32 %0, %1, %2" : "=v"(r) : "v"(lo), "v"(hi));
    return r;
}
__device__ __forceinline__ float exp2_asm(float x) {
    float r; asm("v_exp_f32 %0, %1" : "=v"(r) : "v"(x)); return r;
}
__device__ __forceinline__ float log2_asm(float x) {
    float r; asm("v_log_f32 %0, %1" : "=v"(r) : "v"(x)); return r;
}
__device__ __forceinline__ void perm32swap(unsigned &a, unsigned &b) {
    u32x2 r = __builtin_amdgcn_permlane32_swap(a, b, false, false);
    a = r[0]; b = r[1];
}
__device__ __forceinline__ void gload16(const short* g, short* l) {
    __builtin_amdgcn_global_load_lds(
        (const __attribute__((address_space(1))) void*)g,
        (__attribute__((address_space(3))) void*)l, 16, 0, 0);
}

// Problem constants
#define BATCH 2
#define CCH   512
#define SSP   4096          // H*W
#define NH    8
#define DH    64

// ---------- kernel 1: weight cast fp32 -> bf16 ----------
__global__ __launch_bounds__(256) void wcast_kernel(
    const float* __restrict__ qw, const float* __restrict__ pw,
    short* __restrict__ dq, short* __restrict__ dp)
{
    int idx = (blockIdx.x * 256 + threadIdx.x) * 8;
    const float* src; short* dst;
    if (idx < 786432) { src = qw + idx; dst = dq + idx; }
    else              { src = pw + (idx - 786432); dst = dp + (idx - 786432); }
    f32x4 a = *(const f32x4*)src;
    f32x4 b = *(const f32x4*)(src + 4);
    s16x8 o;
    o[0]=f2bf(a[0]); o[1]=f2bf(a[1]); o[2]=f2bf(a[2]); o[3]=f2bf(a[3]);
    o[4]=f2bf(b[0]); o[5]=f2bf(b[1]); o[6]=f2bf(b[2]); o[7]=f2bf(b[3]);
    *(s16x8*)dst = o;
}

// ---------- kernel 2: GroupNorm partial sums ----------
__global__ __launch_bounds__(256) void gn_partial_kernel(
    const float* __restrict__ x, float* __restrict__ part)
{
    int bg = blockIdx.x >> 5, chunk = blockIdx.x & 31;
    const float* base = x + (size_t)bg * 262144 + chunk * 8192;
    int t = threadIdx.x, lane = t & 63, wave = t >> 6;
    float s = 0.f, ss = 0.f;
    #pragma unroll
    for (int k = 0; k < 8; ++k) {
        f32x4 v = *(const f32x4*)&base[k * 1024 + t * 4];
        #pragma unroll
        for (int j = 0; j < 4; ++j) { s += v[j]; ss += v[j] * v[j]; }
    }
    #pragma unroll
    for (int mask = 1; mask < 64; mask <<= 1) {
        s  += __shfl_xor(s,  mask);
        ss += __shfl_xor(ss, mask);
    }
    __shared__ float rs[4], rss[4];
    if (lane == 0) { rs[wave] = s; rss[wave] = ss; }
    __syncthreads();
    if (t == 0) {
        part[blockIdx.x * 2]     = rs[0] + rs[1] + rs[2] + rs[3];
        part[blockIdx.x * 2 + 1] = rss[0] + rss[1] + rss[2] + rss[3];
    }
}

// ---------- kernel 3: finalize mean/rstd ----------
__global__ void gn_final_kernel(const float* __restrict__ part, float* __restrict__ stats)
{
    int t = threadIdx.x;
    if (t < 16) {
        float s = 0.f, ss = 0.f;
        for (int c = 0; c < 32; ++c) {
            s  += part[(t * 32 + c) * 2];
            ss += part[(t * 32 + c) * 2 + 1];
        }
        float mean = s * (1.f / 262144.f);
        float var  = ss * (1.f / 262144.f) - mean * mean;
        stats[t * 2]     = mean;
        stats[t * 2 + 1] = rsqrtf(var + 1e-5f);
    }
}

// ---------- kernel 4: normalize + transpose -> h[M=8192][K=512] bf16 ----------
__global__ __launch_bounds__(256) void gn_apply_kernel(
    const float* __restrict__ x, const float* __restrict__ gw, const float* __restrict__ gb,
    const float* __restrict__ stats, short* __restrict__ hbuf)
{
    __shared__ float tile[64][65];
    int id = blockIdx.x;
    int st = id & 63, ct = (id >> 6) & 7, b = id >> 9;
    int t  = threadIdx.x;
    float mean = stats[(b * 8 + ct) * 2], rstd = stats[(b * 8 + ct) * 2 + 1];
    #pragma unroll
    for (int pass = 0; pass < 4; ++pass) {
        int cr = pass * 16 + (t >> 4);
        int c  = ct * 64 + cr;
        f32x4 v = *(const f32x4*)&x[((size_t)(b * CCH + c)) * SSP + st * 64 + (t & 15) * 4];
        float w  = gw[c] * rstd;
        float bb = gb[c] - mean * w;
        #pragma unroll
        for (int j = 0; j < 4; ++j) tile[cr][(t & 15) * 4 + j] = v[j] * w + bb;
    }
    __syncthreads();
    int sr = t >> 2, cc0 = (t & 3) * 16;
    s16x8 o0, o1;
    #pragma unroll
    for (int j = 0; j < 8; ++j) {
        o0[j] = f2bf(tile[cc0 + j][sr]);
        o1[j] = f2bf(tile[cc0 + 8 + j][sr]);
    }
    short* dst = &hbuf[(size_t)(b * SSP + st * 64 + sr) * CCH + ct * 64 + cc0];
    *(s16x8*)dst = o0;
    *(s16x8*)(dst + 8) = o1;
}

// ---------- GEMM: C[M,N] = A[M,K] * Bt[N,K]^T, bf16 in, fp32 acc ----------
// EPI 0: qkv epilogue. Q pixel-major [8192][512].
//   K -> 32x32 A-frag-linear: elem K[t][d] at [bh][T=t>>6][f=tb*4+(d>>4)][l=(t&31)+32*((d>>3)&1)][j=d&7]
//   V -> 32x32 A-frag-linear: elem V[t][d] at [bh][T][f=(d>>5)*4+((t>>4)&3)][l=(d&31)+32*((t>>3)&1)][j=t&7]
// EPI 1: proj epilogue (transpose to NCHW + residual + bias, fp32 out)
template<int EPI>
__global__ __launch_bounds__(256) void gemm_bt_kernel(
    const short* __restrict__ A, const short* __restrict__ Bt,
    const float* __restrict__ bias,
    short* __restrict__ qout, short* __restrict__ kout, short* __restrict__ vout,
    const float* __restrict__ xres, float* __restrict__ out,
    int K)
{
    __shared__ short As[4096], Bs[4096];
    const int t = threadIdx.x;
    const int lane = t & 63, wave = t >> 6;
    const int wm = wave >> 1, wn = wave & 1;
    const int m0 = blockIdx.x * 128, n0 = blockIdx.y * 128;
    const int l15 = lane & 15, lq = lane >> 4;

    f32x4 acc[4][4];
    #pragma unroll
    for (int i = 0; i < 4; ++i)
        #pragma unroll
        for (int j = 0; j < 4; ++j) acc[i][j] = (f32x4){0.f, 0.f, 0.f, 0.f};

    for (int kk = 0; kk < K; kk += 32) {
        __syncthreads();
        #pragma unroll
        for (int i = 0; i < 2; ++i) {
            int idx = i * 256 + t;
            int row = idx >> 2, cb = idx & 3;
            int dst = ((row >> 4) << 9) + ((((row & 15)) | (cb << 4)) << 3);
            *(s16x8*)&As[dst] = *(const s16x8*)&A [(size_t)(m0 + row) * K + kk + cb * 8];
            *(s16x8*)&Bs[dst] = *(const s16x8*)&Bt[(size_t)(n0 + row) * K + kk + cb * 8];
        }
        __syncthreads();
        s16x8 af[4], bfr[4];
        #pragma unroll
        for (int mt = 0; mt < 4; ++mt) af[mt]  = *(const s16x8*)&As[(((wm * 4 + mt) << 9) + lane * 8)];
        #pragma unroll
        for (int nt = 0; nt < 4; ++nt) bfr[nt] = *(const s16x8*)&Bs[(((wn * 4 + nt) << 9) + lane * 8)];
        #pragma unroll
        for (int mt = 0; mt < 4; ++mt)
            #pragma unroll
            for (int nt = 0; nt < 4; ++nt)
                acc[mt][nt] = __builtin_amdgcn_mfma_f32_16x16x32_bf16(af[mt], bfr[nt], acc[mt][nt], 0, 0, 0);
    }

    #pragma unroll
    for (int mt = 0; mt < 4; ++mt) {
        const int r0 = m0 + wm * 64 + mt * 16 + lq * 4;
        #pragma unroll
        for (int nt = 0; nt < 4; ++nt) {
            const int c = n0 + wn * 64 + nt * 16 + l15;
            float bv = bias[c];
            if (EPI == 0) {
                int bb = r0 >> 12, tloc = r0 & 4095;
                if (c < 512) {
                    #pragma unroll
                    for (int i = 0; i < 4; ++i)
                        qout[(size_t)(r0 + i) * 512 + c] = f2bf(acc[mt][nt][i] + bv);
                } else if (c < 1024) {
                    int hh = (c - 512) >> 6, d = (c - 512) & 63;
                    int T = tloc >> 6, tb = (tloc >> 5) & 1;
                    size_t base = (((size_t)(bb * 8 + hh) * 64 + T) * 8 + tb * 4 + (d >> 4)) * 512
                                  + 256 * ((d >> 3) & 1) + (d & 7);
                    #pragma unroll
                    for (int i = 0; i < 4; ++i)
                        kout[base + ((tloc & 31) + i) * 8] = f2bf(acc[mt][nt][i] + bv);
                } else {
                    int hh = (c - 1024) >> 6, d = (c - 1024) & 63;
                    int T = tloc >> 6, s = (tloc >> 4) & 3, thi = (tloc >> 3) & 1, j0 = tloc & 7;
                    size_t base = (((size_t)(bb * 8 + hh) * 64 + T) * 8 + (d >> 5) * 4 + s) * 512
                                  + ((d & 31) + 32 * thi) * 8 + j0;
                    s16x4 pv;
                    #pragma unroll
                    for (int i = 0; i < 4; ++i) pv[i] = f2bf(acc[mt][nt][i] + bv);
                    *(s16x4*)&vout[base] = pv;
                }
            } else {
                int bb = r0 >> 12, s = r0 & 4095;
                size_t xi = (size_t)(bb * CCH + c) * SSP + s;
                f32x4 xv = *(const f32x4*)&xres[xi];
                f32x4 o  = xv + acc[mt][nt] + bv;
                *(f32x4*)&out[xi] = o;
            }
        }
    }
}

// ---------- kernel 6: flash attention, 32x32 MFMA, permlane P-exchange ----------
// grid (32, 32): x = q-tile (128 rows/block, 32/wave), y = half*16 + bh
__global__ __launch_bounds__(256, 4) void attn_kernel(
    const short* __restrict__ qbuf, const short* __restrict__ kfrag,
    const short* __restrict__ vfrag,
    short* __restrict__ p0, short* __restrict__ p1, float* __restrict__ aout)
{
    __shared__ short Ks[2][4096];
    __shared__ short Vs[2][4096];
    const int t = threadIdx.x, lane = t & 63, wave = t >> 6;
    const int yy = blockIdx.y, bh = yy & 15, half = yy >> 4;
    const int b = bh >> 3, h = bh & 7;
    const int q0w = blockIdx.x * 128 + wave * 32;
    const int l31 = lane & 31, lh = lane >> 5;
    const int kv0 = half * 2048;

    // Q as B-operand: col=q=l31, k_d = 16s + 8*lh + j ; prescaled by 0.125*log2(e)
    s16x8 qf[4];
    {
        const short* qp = qbuf + (size_t)(b * SSP + q0w + l31) * 512 + h * 64 + 8 * lh;
        #pragma unroll
        for (int s = 0; s < 4; ++s) {
            s16x8 raw = *(const s16x8*)(qp + 16 * s);
            #pragma unroll
            for (int j = 0; j < 8; ++j) qf[s][j] = f2bf(bf2f(raw[j]) * 0.18033688011112042f);
        }
    }

    const short* kbase = kfrag + (size_t)bh * 262144 + lane * 8;
    const short* vbase = vfrag + (size_t)bh * 262144 + lane * 8;

    f32x16 oacc[2];
    oacc[0] = (f32x16){}; oacc[1] = (f32x16){};
    float m_ = -__builtin_inff(), l_ = 0.f;

    // prologue stage
    {
        const short* kg = kbase + (size_t)(kv0 >> 6) * 4096 + wave * 1024;
        gload16(kg,       &Ks[0][wave * 1024]);
        gload16(kg + 512, &Ks[0][wave * 1024 + 512]);
        const short* vg = vbase + (size_t)(kv0 >> 6) * 4096 + wave * 1024;
        gload16(vg,       &Vs[0][wave * 1024]);
        gload16(vg + 512, &Vs[0][wave * 1024 + 512]);
    }
    asm volatile("s_waitcnt vmcnt(0)" ::: "memory");
    __syncthreads();

    int cur = 0;
    for (int t0 = kv0; t0 < kv0 + 2048; t0 += 64) {
        if (t0 + 64 < kv0 + 2048) {
            int nb = cur ^ 1;
            const short* kg = kbase + (size_t)((t0 + 64) >> 6) * 4096 + wave * 1024;
            gload16(kg,       &Ks[nb][wave * 1024]);
            gload16(kg + 512, &Ks[nb][wave * 1024 + 512]);
            const short* vg = vbase + (size_t)((t0 + 64) >> 6) * 4096 + wave * 1024;
            gload16(vg,       &Vs[nb][wave * 1024]);
            gload16(vg + 512, &Vs[nb][wave * 1024 + 512]);
        }

        // ---- S^T = K * Q^T (log2 domain): sacc[tb] col=q=l31, row=t ----
        f32x16 sacc[2];
        sacc[0] = (f32x16){}; sacc[1] = (f32x16){};
        __builtin_amdgcn_s_setprio(1);
        #pragma unroll
        for (int s = 0; s < 4; ++s) {
            s16x8 k0 = *(const s16x8*)&Ks[cur][(0 + s) * 512 + lane * 8];
            s16x8 k1 = *(const s16x8*)&Ks[cur][(4 + s) * 512 + lane * 8];
            sacc[0] = __builtin_amdgcn_mfma_f32_32x32x16_bf16(k0, qf[s], sacc[0], 0, 0, 0);
            sacc[1] = __builtin_amdgcn_mfma_f32_32x32x16_bf16(k1, qf[s], sacc[1], 0, 0, 0);
        }
        __builtin_amdgcn_s_setprio(0);

        // ---- softmax (scalar m/l per lane; defer-max) ----
        float mx = sacc[0][0];
        #pragma unroll
        for (int r = 1; r < 16; ++r) mx = fmaxf(mx, sacc[0][r]);
        #pragma unroll
        for (int r = 0; r < 16; ++r) mx = fmaxf(mx, sacc[1][r]);
        int calm = __all(mx <= m_ + 11.5f);
        if (!calm) {
            float g = fmaxf(mx, __shfl_xor(mx, 32));
            float mn = fmaxf(m_, g);
            float corr = exp2_asm(m_ - mn);
            m_ = mn;
            #pragma unroll
            for (int r = 0; r < 16; ++r) { oacc[0][r] *= corr; oacc[1][r] *= corr; }
            l_ *= corr;
        }
        float ts = 0.f;
        #pragma unroll
        for (int tb = 0; tb < 2; ++tb)
            #pragma unroll
            for (int r = 0; r < 16; ++r) {
                float e = exp2_asm(sacc[tb][r] - m_);
                sacc[tb][r] = e;
                ts += e;
            }
        ts += __shfl_xor(ts, 32);
        l_ += ts;

        // ---- P pack + permlane exchange -> B-operand words ----
        unsigned w[16];
        #pragma unroll
        for (int tb = 0; tb < 2; ++tb)
            #pragma unroll
            for (int r = 0; r < 8; ++r)
                w[tb * 8 + r] = cvt_pk_bf16(sacc[tb][2 * r], sacc[tb][2 * r + 1]);
        #pragma unroll
        for (int s = 0; s < 4; ++s) {
            perm32swap(w[s * 4 + 0], w[s * 4 + 2]);
            perm32swap(w[s * 4 + 1], w[s * 4 + 3]);
        }

        // ---- O^T += V^T * P^T : oacc[db] col=q, row=d ----
        __builtin_amdgcn_s_setprio(1);
        #pragma unroll
        for (int s = 0; s < 4; ++s) {
            u32x4 pb = { w[s * 4 + 0], w[s * 4 + 1], w[s * 4 + 2], w[s * 4 + 3] };
            s16x8 pB = __builtin_bit_cast(s16x8, pb);
            s16x8 v0 = *(const s16x8*)&Vs[cur][(0 + s) * 512 + lane * 8];
            s16x8 v1 = *(const s16x8*)&Vs[cur][(4 + s) * 512 + lane * 8];
            oacc[0] = __builtin_amdgcn_mfma_f32_32x32x16_bf16(v0, pB, oacc[0], 0, 0, 0);
            oacc[1] = __builtin_amdgcn_mfma_f32_32x32x16_bf16(v1, pB, oacc[1], 0, 0, 0);
        }
        __builtin_amdgcn_s_setprio(0);

        asm volatile("s_waitcnt vmcnt(0)" ::: "memory");
        __syncthreads();
        cur ^= 1;
    }

    // epilogue: normalized partial O [bh][q][d] + a = m + log2(l)
    short* pO = half ? p1 : p0;
    float linv = 1.f / l_;
    int q = q0w + l31;
    size_t obase = ((size_t)bh * 4096 + q) * 64;
    #pragma unroll
    for (int db = 0; db < 2; ++db)
        #pragma unroll
        for (int g = 0; g < 4; ++g) {
            s16x4 o;
            #pragma unroll
            for (int i = 0; i < 4; ++i) o[i] = f2bf(oacc[db][g * 4 + i] * linv);
            *(s16x4*)&pO[obase + db * 32 + g * 8 + lh * 4] = o;
        }
    if (lh == 0)
        aout[half * 65536 + bh * 4096 + q] = m_ + log2_asm(l_);
}

// ---------- kernel 7: combine kv-split halves ----------
__global__ __launch_bounds__(256) void combine_kernel(
    const short* __restrict__ p0, const short* __restrict__ p1,
    const float* __restrict__ aout, short* __restrict__ ao)
{
    int bh = blockIdx.x >> 7, q = (blockIdx.x & 127) * 32 + (threadIdx.x >> 3);
    int d0 = (threadIdx.x & 7) * 8;
    size_t pi = ((size_t)bh * 4096 + q) * 64 + d0;
    s16x8 o1 = *(const s16x8*)&p0[pi];
    s16x8 o2 = *(const s16x8*)&p1[pi];
    float a1 = aout[bh * 4096 + q], a2 = aout[65536 + bh * 4096 + q];
    float M = fmaxf(a1, a2);
    float w1 = exp2_asm(a1 - M), w2 = exp2_asm(a2 - M);
    float inv = 1.f / (w1 + w2);
    w1 *= inv; w2 *= inv;
    s16x8 o;
    #pragma unroll
    for (int j = 0; j < 8; ++j) o[j] = f2bf(bf2f(o1[j]) * w1 + bf2f(o2[j]) * w2);
    int b = bh >> 3, h = bh & 7;
    *(s16x8*)&ao[(size_t)(b * SSP + q) * 512 + h * 64 + d0] = o;
}

// ---------- launch ----------
extern "C" void kernel_launch(void* const* d_in, const int* in_sizes, int n_in,
                              void* d_out, int out_size, void* d_ws, size_t ws_size,
                              hipStream_t stream)
{
    (void)in_sizes; (void)n_in; (void)out_size; (void)ws_size;
    const float* x      = (const float*)d_in[0];
    const float* gn_w   = (const float*)d_in[1];
    const float* gn_b   = (const float*)d_in[2];
    const float* qkv_w  = (const float*)d_in[3];
    const float* qkv_b  = (const float*)d_in[4];
    const float* proj_w = (const float*)d_in[5];
    const float* proj_b = (const float*)d_in[6];
    float* out = (float*)d_out;
    char* ws = (char*)d_ws;

    short* hbuf  = (short*)(ws + 0);          //  8 MB  h[8192][512]  (reused: partial O half 0)
    short* qbuf  = (short*)(ws + 8388608);    //  8 MB  q[8192][512]
    short* kfrag = (short*)(ws + 16777216);   //  8 MB  k 32x32-frag-linear (reused: combined O)
    short* vfrag = (short*)(ws + 25165824);   //  8 MB  v 32x32-frag-linear
    short* aobuf = (short*)(ws + 33554432);   //  8 MB  (partial O half 1)
    short* wqkv  = (short*)(ws + 41943040);   //  1.5 MB (reused: a-scalars 512KB)
    short* wproj = (short*)(ws + 43515904);   //  0.5 MB
    float* part  = (float*)(ws + 44040192);
    float* stats = (float*)(ws + 44044288);
    float* ascal = (float*)(ws + 41943040);

    wcast_kernel<<<512, 256, 0, stream>>>(qkv_w, proj_w, wqkv, wproj);
    gn_partial_kernel<<<512, 256, 0, stream>>>(x, part);
    gn_final_kernel<<<1, 64, 0, stream>>>(part, stats);
    gn_apply_kernel<<<1024, 256, 0, stream>>>(x, gn_w, gn_b, stats, hbuf);
    gemm_bt_kernel<0><<<dim3(64, 12), 256, 0, stream>>>(hbuf, wqkv, qkv_b,
                                                        qbuf, kfrag, vfrag, nullptr, nullptr, 512);
    attn_kernel<<<dim3(32, 32), 256, 0, stream>>>(qbuf, kfrag, vfrag,
                                                  hbuf, aobuf, ascal);
    combine_kernel<<<2048, 256, 0, stream>>>(hbuf, aobuf, ascal, kfrag);
    gemm_bt_kernel<1><<<dim3(64, 4), 256, 0, stream>>>(kfrag, wproj, proj_b,
                                                       nullptr, nullptr, nullptr, x, out, 512);
}